// Round 1
// baseline (164.158 us; speedup 1.0000x reference)
//
#include <hip/hip_runtime.h>

#define B_    64
#define HW_   196
#define HWP_  224
#define D_    768
#define E_    256
#define C_    10
#define MP_   (B_*HWP_)   // 14336 padded rows
#define K3K_  (E_*D_)     // 196608 deep-K for final contraction
#define K3NB_ 192         // K-split blocks for k3

typedef __bf16 bf16x8 __attribute__((ext_vector_type(8)));
typedef __bf16 bf16x4 __attribute__((ext_vector_type(4)));
typedef float  f32x4  __attribute__((ext_vector_type(4)));

// async global->LDS, 16B per lane; LDS dest is wave-uniform base + lane*16
__device__ __forceinline__ void gld_lds16(const void* g, void* l) {
  __builtin_amdgcn_global_load_lds((const __attribute__((address_space(1))) void*)g,
                                   (__attribute__((address_space(3))) void*)l, 16, 0, 0);
}

// ---------------- K0x: fp32 x -> bf16 hi/lo, zero-padded [B][HWP][D] ----------------
__global__ __launch_bounds__(256) void k0_x(const float* __restrict__ x,
                                            __bf16* __restrict__ xhi,
                                            __bf16* __restrict__ xlo) {
  size_t i4 = ((size_t)blockIdx.x * 256 + threadIdx.x) * 4;
  int d  = (int)(i4 % D_);
  size_t row = i4 / D_;
  int hp = (int)(row % HWP_);
  int b  = (int)(row / HWP_);
  float4 v = make_float4(0.f, 0.f, 0.f, 0.f);
  if (hp < HW_) v = *(const float4*)&x[((size_t)b * HW_ + hp) * D_ + d];
  float vv[4] = {v.x, v.y, v.z, v.w};
  bf16x4 h, l;
#pragma unroll
  for (int j = 0; j < 4; j++) {
    __bf16 hj = (__bf16)vv[j];
    float r = vv[j] - (float)hj;
    h[j] = hj;
    l[j] = (__bf16)r;
  }
  *(bf16x4*)&xhi[i4] = h;
  *(bf16x4*)&xlo[i4] = l;
}

// ---------------- K0prep: merged {ag_w -> bf16 hi/lo} and {lm_w -> W2 permute} --------
// blocks [0,192): ag_w split (E*D/4/256 = 192)
// blocks [192, 192+3072): w2[c][e*768+d], c padded to 16; w2 linear index == i4
__global__ __launch_bounds__(256) void k0_prep(const float* __restrict__ w,
                                               __bf16* __restrict__ whi,
                                               __bf16* __restrict__ wlo,
                                               const float* __restrict__ lmw,
                                               __bf16* __restrict__ w2) {
  int bid = blockIdx.x;
  if (bid < 192) {
    size_t i4 = ((size_t)bid * 256 + threadIdx.x) * 4;
    float4 v = *(const float4*)&w[i4];
    float vv[4] = {v.x, v.y, v.z, v.w};
    bf16x4 h, l;
#pragma unroll
    for (int j = 0; j < 4; j++) {
      __bf16 hj = (__bf16)vv[j];
      float r = vv[j] - (float)hj;
      h[j] = hj;
      l[j] = (__bf16)r;
    }
    *(bf16x4*)&whi[i4] = h;
    *(bf16x4*)&wlo[i4] = l;
  } else {
    size_t i4 = ((size_t)(bid - 192) * 256 + threadIdx.x) * 4;  // < 16*K3K_
    int c = (int)(i4 / K3K_);
    int rem = (int)(i4 - (size_t)c * K3K_);
    int e = rem / D_;
    int d = rem - e * D_;
    bf16x4 o;
    if (c < C_) {
      float4 v = *(const float4*)&lmw[((size_t)e * C_ + c) * D_ + d];
      o[0] = (__bf16)v.x; o[1] = (__bf16)v.y; o[2] = (__bf16)v.z; o[3] = (__bf16)v.w;
    } else {
      o[0] = o[1] = o[2] = o[3] = (__bf16)0.0f;
    }
    *(bf16x4*)&w2[i4] = o;
  }
}

// ---------------- K1: sign GEMM, 3-term split-bf16 MFMA ----------------
// 64x64 tiles, 4 waves each 32x32 (2x2 frags), grid 224x4 = 896 blocks.
// Staging now via global_load_lds (no VGPR roundtrip, no LDS write instrs).
// LDS linear stride 32 (gload_lds requires contiguous lane order); read-side
// 8-way conflicts are hidden by the 2-phase barrier drain (m252).
__global__ __launch_bounds__(256) void k1_signs(const __bf16* __restrict__ xhi,
                                                const __bf16* __restrict__ xlo,
                                                const __bf16* __restrict__ whi,
                                                const __bf16* __restrict__ wlo,
                                                const float* __restrict__ bias,
                                                __bf16* __restrict__ st) {
  __shared__ __align__(16) __bf16 Ah[64 * 32];
  __shared__ __align__(16) __bf16 Al[64 * 32];
  __shared__ __align__(16) __bf16 Bh[64 * 32];
  __shared__ __align__(16) __bf16 Bl[64 * 32];
  const int m0 = blockIdx.x * 64;
  const int n0 = blockIdx.y * 64;
  const int tid = threadIdx.x;
  const int wave = tid >> 6, lane = tid & 63;
  const int wm = (wave & 1) * 32, wn = (wave >> 1) * 32;
  const int q = lane >> 4, l15 = lane & 15;
  const int sr = tid >> 2;          // staging row 0..63 (= wave*16 + lane/4)
  const int sk = (tid & 3) * 8;     // staging k-offset
  const int ldsoff = wave * 512;    // wave-uniform LDS elem base (16 rows * 32)
  f32x4 acc[2][2] = {};

  for (int k0 = 0; k0 < D_; k0 += 32) {
    __syncthreads();
    gld_lds16(&xhi[(size_t)(m0 + sr) * D_ + k0 + sk], &Ah[ldsoff]);
    gld_lds16(&xlo[(size_t)(m0 + sr) * D_ + k0 + sk], &Al[ldsoff]);
    gld_lds16(&whi[(size_t)(n0 + sr) * D_ + k0 + sk], &Bh[ldsoff]);
    gld_lds16(&wlo[(size_t)(n0 + sr) * D_ + k0 + sk], &Bl[ldsoff]);
    __syncthreads();   // compiler emits vmcnt(0) drain here -> LDS valid
    bf16x8 af[2], alf[2], bfh[2], bfl[2];
#pragma unroll
    for (int t = 0; t < 2; t++) {
      af[t]  = *(const bf16x8*)&Ah[(wm + t * 16 + l15) * 32 + q * 8];
      alf[t] = *(const bf16x8*)&Al[(wm + t * 16 + l15) * 32 + q * 8];
      bfh[t] = *(const bf16x8*)&Bh[(wn + t * 16 + l15) * 32 + q * 8];
      bfl[t] = *(const bf16x8*)&Bl[(wn + t * 16 + l15) * 32 + q * 8];
    }
#pragma unroll
    for (int mt = 0; mt < 2; mt++)
#pragma unroll
      for (int nt = 0; nt < 2; nt++) {
        acc[mt][nt] = __builtin_amdgcn_mfma_f32_16x16x32_bf16(af[mt],  bfh[nt], acc[mt][nt], 0, 0, 0);
        acc[mt][nt] = __builtin_amdgcn_mfma_f32_16x16x32_bf16(alf[mt], bfh[nt], acc[mt][nt], 0, 0, 0);
        acc[mt][nt] = __builtin_amdgcn_mfma_f32_16x16x32_bf16(af[mt],  bfl[nt], acc[mt][nt], 0, 0, 0);
      }
  }
#pragma unroll
  for (int mt = 0; mt < 2; mt++)
#pragma unroll
    for (int nt = 0; nt < 2; nt++) {
      int e = n0 + wn + nt * 16 + l15;
      float bv = bias[e];
#pragma unroll
      for (int r = 0; r < 4; r++) {
        int m = m0 + wm + mt * 16 + q * 4 + r;   // C/D: row=quad*4+reg, col=lane&15
        int b = m / HWP_;
        int hp = m - b * HWP_;
        float v = acc[mt][nt][r] + bv;
        __bf16 s = (hp < HW_ && v > 0.0f) ? (__bf16)1.0f : (__bf16)0.0f;
        st[((size_t)b * E_ + e) * HWP_ + hp] = s;
      }
    }
}

// ---------------- K2: per-batch G = S^T · X  (M=256 e, N=768 d, K=224 hp) ----------------
// As via global_load_lds (linear stride 32). Bs transpose staging rewritten:
// old: 16x ds_write_b16/thread with bank=(20*(dc0+j)+kk/2)%32 -> d contributes 0
//      (16*80B == 0 mod 128B) -> 16-way conflict on 22M writes.
// new: thread owns 4k x 4d micro-tile -> 4x ds_write_b64; bank =
//      (16*(dgroup&1) + 20j + 2*kquad)%32 -> all 32 banks, <=4-way.
__global__ __launch_bounds__(256) void k2_g(const __bf16* __restrict__ st,
                                            const __bf16* __restrict__ xhi,
                                            __bf16* __restrict__ g) {
  __shared__ __align__(16) __bf16 As[128 * 32];
  __shared__ __align__(16) __bf16 Bs[128 * 40];   // Bs[d][k], stride 40 keeps reads ~2-way
  const int b  = blockIdx.y;
  const int e0 = (blockIdx.x / 6) * 128;
  const int d0 = (blockIdx.x % 6) * 128;
  const int tid = threadIdx.x;
  const int wave = tid >> 6, lane = tid & 63;
  const int wm = (wave & 1) * 64, wn = (wave >> 1) * 64;
  const int q = lane >> 4, l15 = lane & 15;
  const int sr = tid >> 2, sk = (tid & 3) * 8;
  const int ldsoff = wave * 512;
  // Bs staging decomposition: tid bits [4:2] -> k-quad, bits [1:0]|[7:5] -> d-group
  const int kk4 = ((tid >> 2) & 7) * 4;                 // k offset 0..28
  const int dgroup = (tid & 3) | (((tid >> 5) & 7) << 2); // 0..31
  const int dc0 = dgroup * 4;                           // d offset 0..124
  f32x4 acc[4][4] = {};

  for (int k0 = 0; k0 < HWP_; k0 += 32) {
    __syncthreads();
    gld_lds16(&st[((size_t)b * E_ + e0 + sr) * HWP_ + k0 + sk],      &As[ldsoff]);
    gld_lds16(&st[((size_t)b * E_ + e0 + 64 + sr) * HWP_ + k0 + sk], &As[64 * 32 + ldsoff]);
    {
      const __bf16* src = &xhi[((size_t)b * HWP_ + k0 + kk4) * D_ + d0 + dc0];
      bf16x4 r0 = *(const bf16x4*)&src[0];
      bf16x4 r1 = *(const bf16x4*)&src[D_];
      bf16x4 r2 = *(const bf16x4*)&src[2 * D_];
      bf16x4 r3 = *(const bf16x4*)&src[3 * D_];
#pragma unroll
      for (int j = 0; j < 4; j++) {
        bf16x4 o;
        o[0] = r0[j]; o[1] = r1[j]; o[2] = r2[j]; o[3] = r3[j];
        *(bf16x4*)&Bs[(dc0 + j) * 40 + kk4] = o;   // 8B-aligned ds_write_b64
      }
    }
    __syncthreads();
    bf16x8 af[4], bfr[4];
#pragma unroll
    for (int t = 0; t < 4; t++) {
      af[t]  = *(const bf16x8*)&As[(wm + t * 16 + l15) * 32 + q * 8];
      bfr[t] = *(const bf16x8*)&Bs[(wn + t * 16 + l15) * 40 + q * 8];
    }
#pragma unroll
    for (int mt = 0; mt < 4; mt++)
#pragma unroll
      for (int nt = 0; nt < 4; nt++)
        acc[mt][nt] = __builtin_amdgcn_mfma_f32_16x16x32_bf16(af[mt], bfr[nt], acc[mt][nt], 0, 0, 0);
  }
#pragma unroll
  for (int mt = 0; mt < 4; mt++)
#pragma unroll
    for (int nt = 0; nt < 4; nt++) {
      int d = d0 + wn + nt * 16 + l15;
#pragma unroll
      for (int r = 0; r < 4; r++) {
        int e = e0 + wm + mt * 16 + q * 4 + r;
        g[((size_t)b * E_ + e) * D_ + d] = (__bf16)acc[mt][nt][r];
      }
    }
}

// ---------------- K3: preds = G_flat(64 x 196608) · W2^T, deep-K split MFMA ----------------
__global__ __launch_bounds__(256) void k3_mfma(const __bf16* __restrict__ g,
                                               const __bf16* __restrict__ w2,
                                               float* __restrict__ out) {
  __shared__ float sp[B_ * C_];
  const int tid = threadIdx.x;
  const int wave = tid >> 6, lane = tid & 63;
  const int q = lane >> 4, l15 = lane & 15;
  const int kbase = blockIdx.x * (K3K_ / K3NB_) + wave * 256;
  f32x4 acc[4] = {};

  for (int i = tid; i < B_ * C_; i += 256) sp[i] = 0.0f;

#pragma unroll
  for (int ks = 0; ks < 8; ks++) {
    int k = kbase + ks * 32 + q * 8;
    bf16x8 bfrag = *(const bf16x8*)&w2[(size_t)l15 * K3K_ + k];
#pragma unroll
    for (int mt = 0; mt < 4; mt++) {
      bf16x8 afrag = *(const bf16x8*)&g[(size_t)(mt * 16 + l15) * K3K_ + k];
      acc[mt] = __builtin_amdgcn_mfma_f32_16x16x32_bf16(afrag, bfrag, acc[mt], 0, 0, 0);
    }
  }
  __syncthreads();
  int c = l15;
  if (c < C_) {
#pragma unroll
    for (int mt = 0; mt < 4; mt++)
#pragma unroll
      for (int r = 0; r < 4; r++) {
        int b = mt * 16 + q * 4 + r;
        atomicAdd(&sp[b * C_ + c], acc[mt][r]);
      }
  }
  __syncthreads();
  const float scale = 1.0f / (196.0f * 256.0f);
  for (int i = tid; i < B_ * C_; i += 256) atomicAdd(&out[i], sp[i] * scale);
}

extern "C" void kernel_launch(void* const* d_in, const int* in_sizes, int n_in,
                              void* d_out, int out_size, void* d_ws, size_t ws_size,
                              hipStream_t stream) {
  const float* x    = (const float*)d_in[0];   // (64,196,768)
  const float* ag_w = (const float*)d_in[1];   // (256,768)
  const float* ag_b = (const float*)d_in[2];   // (256,)
  const float* lm_w = (const float*)d_in[3];   // (2560,768)
  float* out = (float*)d_out;                  // (64,10)

  char* ws = (char*)d_ws;
  const size_t XP_BYTES = (size_t)B_ * HWP_ * D_ * 2;
  const size_t W_BYTES  = (size_t)E_ * D_ * 2;
  const size_t ST_BYTES = (size_t)B_ * E_ * HWP_ * 2;
  const size_t G_BYTES  = (size_t)B_ * E_ * D_ * 2;
  __bf16* xhi = (__bf16*)(ws);
  __bf16* xlo = (__bf16*)(ws + XP_BYTES);
  __bf16* whi = (__bf16*)(ws + 2 * XP_BYTES);
  __bf16* wlo = (__bf16*)(ws + 2 * XP_BYTES + W_BYTES);
  __bf16* st  = (__bf16*)(ws + 2 * XP_BYTES + 2 * W_BYTES);
  __bf16* gb  = (__bf16*)(ws + 2 * XP_BYTES + 2 * W_BYTES + ST_BYTES);
  __bf16* w2  = (__bf16*)(ws + 2 * XP_BYTES + 2 * W_BYTES + ST_BYTES + G_BYTES);

  hipMemsetAsync(d_out, 0, (size_t)out_size * sizeof(float), stream);

  k0_x<<<dim3((B_ * HWP_ * D_) / 4 / 256), dim3(256), 0, stream>>>(x, xhi, xlo);
  // 192 blocks of ag_w split + 3072 blocks of w2 permute (16*K3K_/4/256)
  k0_prep<<<dim3(192 + (16 * K3K_) / 4 / 256), dim3(256), 0, stream>>>(ag_w, whi, wlo, lm_w, w2);
  k1_signs<<<dim3(MP_ / 64, E_ / 64), dim3(256), 0, stream>>>(xhi, xlo, whi, wlo, ag_b, st);
  k2_g<<<dim3((E_ / 128) * (D_ / 128), B_), dim3(256), 0, stream>>>(st, xhi, gb);
  k3_mfma<<<dim3(K3NB_), dim3(256), 0, stream>>>(gb, w2, out);
}

// Round 2
// 163.308 us; speedup vs baseline: 1.0052x; 1.0052x over previous
//
#include <hip/hip_runtime.h>

#define B_    64
#define HW_   196
#define HWP_  224
#define D_    768
#define E_    256
#define C_    10
#define MP_   (B_*HWP_)   // 14336 padded rows
#define K3K_  (E_*D_)     // 196608 deep-K for final contraction
#define K3NB_ 192         // K-split blocks for k3

typedef __bf16 bf16x8 __attribute__((ext_vector_type(8)));
typedef __bf16 bf16x4 __attribute__((ext_vector_type(4)));
typedef float  f32x4  __attribute__((ext_vector_type(4)));

// async global->LDS, 16B per lane; LDS dest is wave-uniform base + lane*16
__device__ __forceinline__ void gld_lds16(const void* g, void* l) {
  __builtin_amdgcn_global_load_lds((const __attribute__((address_space(1))) void*)g,
                                   (__attribute__((address_space(3))) void*)l, 16, 0, 0);
}

// ---------------- K0x: fp32 x -> bf16 hi/lo, zero-padded [B][HWP][D] ----------------
__global__ __launch_bounds__(256) void k0_x(const float* __restrict__ x,
                                            __bf16* __restrict__ xhi,
                                            __bf16* __restrict__ xlo) {
  size_t i4 = ((size_t)blockIdx.x * 256 + threadIdx.x) * 4;
  int d  = (int)(i4 % D_);
  size_t row = i4 / D_;
  int hp = (int)(row % HWP_);
  int b  = (int)(row / HWP_);
  float4 v = make_float4(0.f, 0.f, 0.f, 0.f);
  if (hp < HW_) v = *(const float4*)&x[((size_t)b * HW_ + hp) * D_ + d];
  float vv[4] = {v.x, v.y, v.z, v.w};
  bf16x4 h, l;
#pragma unroll
  for (int j = 0; j < 4; j++) {
    __bf16 hj = (__bf16)vv[j];
    float r = vv[j] - (float)hj;
    h[j] = hj;
    l[j] = (__bf16)r;
  }
  *(bf16x4*)&xhi[i4] = h;
  *(bf16x4*)&xlo[i4] = l;
}

// ---------------- K0prep: merged {ag_w -> bf16 hi/lo} and {lm_w -> W2 permute} --------
__global__ __launch_bounds__(256) void k0_prep(const float* __restrict__ w,
                                               __bf16* __restrict__ whi,
                                               __bf16* __restrict__ wlo,
                                               const float* __restrict__ lmw,
                                               __bf16* __restrict__ w2) {
  int bid = blockIdx.x;
  if (bid < 192) {
    size_t i4 = ((size_t)bid * 256 + threadIdx.x) * 4;
    float4 v = *(const float4*)&w[i4];
    float vv[4] = {v.x, v.y, v.z, v.w};
    bf16x4 h, l;
#pragma unroll
    for (int j = 0; j < 4; j++) {
      __bf16 hj = (__bf16)vv[j];
      float r = vv[j] - (float)hj;
      h[j] = hj;
      l[j] = (__bf16)r;
    }
    *(bf16x4*)&whi[i4] = h;
    *(bf16x4*)&wlo[i4] = l;
  } else {
    size_t i4 = ((size_t)(bid - 192) * 256 + threadIdx.x) * 4;  // < 16*K3K_
    int c = (int)(i4 / K3K_);
    int rem = (int)(i4 - (size_t)c * K3K_);
    int e = rem / D_;
    int d = rem - e * D_;
    bf16x4 o;
    if (c < C_) {
      float4 v = *(const float4*)&lmw[((size_t)e * C_ + c) * D_ + d];
      o[0] = (__bf16)v.x; o[1] = (__bf16)v.y; o[2] = (__bf16)v.z; o[3] = (__bf16)v.w;
    } else {
      o[0] = o[1] = o[2] = o[3] = (__bf16)0.0f;
    }
    *(bf16x4*)&w2[i4] = o;
  }
}

// ---------------- K1: sign GEMM, 3-term split-bf16 MFMA ----------------
// 64x64 tiles, 4 waves each 32x32 (2x2 frags), grid 224x4 = 896 blocks.
// R1 profile: MfmaUtil 14.6%, VALU 11%, HBM 10%, occ 25% -> latency-bound on the
// 2-barrier stage/compute pattern. Now: double-buffered LDS + prefetch-ahead
// (T3 minimal 2-phase), ONE __syncthreads per k-step; its vmcnt(0) drain is
// overlapped by the ds_read+MFMA phase of the current tile.
__global__ __launch_bounds__(256) void k1_signs(const __bf16* __restrict__ xhi,
                                                const __bf16* __restrict__ xlo,
                                                const __bf16* __restrict__ whi,
                                                const __bf16* __restrict__ wlo,
                                                const float* __restrict__ bias,
                                                __bf16* __restrict__ st) {
  __shared__ __align__(16) __bf16 Ah[2][64 * 32];
  __shared__ __align__(16) __bf16 Al[2][64 * 32];
  __shared__ __align__(16) __bf16 Bh[2][64 * 32];
  __shared__ __align__(16) __bf16 Bl[2][64 * 32];
  const int m0 = blockIdx.x * 64;
  const int n0 = blockIdx.y * 64;
  const int tid = threadIdx.x;
  const int wave = tid >> 6, lane = tid & 63;
  const int wm = (wave & 1) * 32, wn = (wave >> 1) * 32;
  const int q = lane >> 4, l15 = lane & 15;
  const int sr = tid >> 2;          // staging row 0..63 (= wave*16 + lane/4)
  const int sk = (tid & 3) * 8;     // staging k-offset
  const int ldsoff = wave * 512;    // wave-uniform LDS elem base (16 rows * 32)
  f32x4 acc[2][2] = {};

  const __bf16* gAh = &xhi[(size_t)(m0 + sr) * D_ + sk];
  const __bf16* gAl = &xlo[(size_t)(m0 + sr) * D_ + sk];
  const __bf16* gBh = &whi[(size_t)(n0 + sr) * D_ + sk];
  const __bf16* gBl = &wlo[(size_t)(n0 + sr) * D_ + sk];

  // prologue: stage tile 0
  gld_lds16(gAh, &Ah[0][ldsoff]);
  gld_lds16(gAl, &Al[0][ldsoff]);
  gld_lds16(gBh, &Bh[0][ldsoff]);
  gld_lds16(gBl, &Bl[0][ldsoff]);
  __syncthreads();

  int cur = 0;
  for (int k0 = 0; k0 < D_; k0 += 32) {
    // prefetch next tile into the other buffer (overlaps with compute below)
    if (k0 + 32 < D_) {
      gld_lds16(gAh + k0 + 32, &Ah[cur ^ 1][ldsoff]);
      gld_lds16(gAl + k0 + 32, &Al[cur ^ 1][ldsoff]);
      gld_lds16(gBh + k0 + 32, &Bh[cur ^ 1][ldsoff]);
      gld_lds16(gBl + k0 + 32, &Bl[cur ^ 1][ldsoff]);
    }
    bf16x8 af[2], alf[2], bfh[2], bfl[2];
#pragma unroll
    for (int t = 0; t < 2; t++) {
      af[t]  = *(const bf16x8*)&Ah[cur][(wm + t * 16 + l15) * 32 + q * 8];
      alf[t] = *(const bf16x8*)&Al[cur][(wm + t * 16 + l15) * 32 + q * 8];
      bfh[t] = *(const bf16x8*)&Bh[cur][(wn + t * 16 + l15) * 32 + q * 8];
      bfl[t] = *(const bf16x8*)&Bl[cur][(wn + t * 16 + l15) * 32 + q * 8];
    }
#pragma unroll
    for (int mt = 0; mt < 2; mt++)
#pragma unroll
      for (int nt = 0; nt < 2; nt++) {
        acc[mt][nt] = __builtin_amdgcn_mfma_f32_16x16x32_bf16(af[mt],  bfh[nt], acc[mt][nt], 0, 0, 0);
        acc[mt][nt] = __builtin_amdgcn_mfma_f32_16x16x32_bf16(alf[mt], bfh[nt], acc[mt][nt], 0, 0, 0);
        acc[mt][nt] = __builtin_amdgcn_mfma_f32_16x16x32_bf16(af[mt],  bfl[nt], acc[mt][nt], 0, 0, 0);
      }
    __syncthreads();   // drains prefetch vmcnt + all lgkm; next iter reads cur^1
    cur ^= 1;
  }
#pragma unroll
  for (int mt = 0; mt < 2; mt++)
#pragma unroll
    for (int nt = 0; nt < 2; nt++) {
      int e = n0 + wn + nt * 16 + l15;
      float bv = bias[e];
#pragma unroll
      for (int r = 0; r < 4; r++) {
        int m = m0 + wm + mt * 16 + q * 4 + r;   // C/D: row=quad*4+reg, col=lane&15
        int b = m / HWP_;
        int hp = m - b * HWP_;
        float v = acc[mt][nt][r] + bv;
        __bf16 s = (hp < HW_ && v > 0.0f) ? (__bf16)1.0f : (__bf16)0.0f;
        st[((size_t)b * E_ + e) * HWP_ + hp] = s;
      }
    }
}

// ---------------- K2: per-batch G = S^T · X  (M=256 e, N=768 d, K=224 hp) ----------------
// Same 2-phase prefetch pipeline. Bs (transposed-on-stage) uses the T14 split:
// global loads for tile k+1 issued BEFORE the MFMA block, ds_write_b64s AFTER it,
// so the compiler's vmcnt wait before the writes is covered by 16 MFMAs.
__global__ __launch_bounds__(256) void k2_g(const __bf16* __restrict__ st,
                                            const __bf16* __restrict__ xhi,
                                            __bf16* __restrict__ g) {
  __shared__ __align__(16) __bf16 As[2][128 * 32];
  __shared__ __align__(16) __bf16 Bs[2][128 * 40];   // Bs[d][k], stride 40
  const int b  = blockIdx.y;
  const int e0 = (blockIdx.x / 6) * 128;
  const int d0 = (blockIdx.x % 6) * 128;
  const int tid = threadIdx.x;
  const int wave = tid >> 6, lane = tid & 63;
  const int wm = (wave & 1) * 64, wn = (wave >> 1) * 64;
  const int q = lane >> 4, l15 = lane & 15;
  const int sr = tid >> 2, sk = (tid & 3) * 8;
  const int ldsoff = wave * 512;
  // Bs staging decomposition: thread owns 4k x 4d micro-tile -> 4x ds_write_b64
  const int kk4 = ((tid >> 2) & 7) * 4;                 // k offset 0..28
  const int dgroup = (tid & 3) | (((tid >> 5) & 7) << 2); // 0..31
  const int dc0 = dgroup * 4;                           // d offset 0..124
  f32x4 acc[4][4] = {};

  const __bf16* gA0 = &st[((size_t)b * E_ + e0 + sr) * HWP_ + sk];
  const __bf16* gA1 = &st[((size_t)b * E_ + e0 + 64 + sr) * HWP_ + sk];
  const __bf16* gB  = &xhi[((size_t)b * HWP_ + kk4) * D_ + d0 + dc0];

  // prologue: stage tile 0 fully
  gld_lds16(gA0, &As[0][ldsoff]);
  gld_lds16(gA1, &As[0][64 * 32 + ldsoff]);
  {
    bf16x4 r0 = *(const bf16x4*)&gB[0];
    bf16x4 r1 = *(const bf16x4*)&gB[D_];
    bf16x4 r2 = *(const bf16x4*)&gB[2 * D_];
    bf16x4 r3 = *(const bf16x4*)&gB[3 * D_];
#pragma unroll
    for (int j = 0; j < 4; j++) {
      bf16x4 o;
      o[0] = r0[j]; o[1] = r1[j]; o[2] = r2[j]; o[3] = r3[j];
      *(bf16x4*)&Bs[0][(dc0 + j) * 40 + kk4] = o;
    }
  }
  __syncthreads();

  int cur = 0;
  for (int k0 = 0; k0 < HWP_; k0 += 32) {
    const bool have = (k0 + 32 < HWP_);
    bf16x4 r0, r1, r2, r3;
    if (have) {
      gld_lds16(gA0 + k0 + 32, &As[cur ^ 1][ldsoff]);
      gld_lds16(gA1 + k0 + 32, &As[cur ^ 1][64 * 32 + ldsoff]);
      const __bf16* src = gB + (size_t)(k0 + 32) * D_;
      r0 = *(const bf16x4*)&src[0];
      r1 = *(const bf16x4*)&src[D_];
      r2 = *(const bf16x4*)&src[2 * D_];
      r3 = *(const bf16x4*)&src[3 * D_];
    }
    bf16x8 af[4], bfr[4];
#pragma unroll
    for (int t = 0; t < 4; t++) {
      af[t]  = *(const bf16x8*)&As[cur][(wm + t * 16 + l15) * 32 + q * 8];
      bfr[t] = *(const bf16x8*)&Bs[cur][(wn + t * 16 + l15) * 40 + q * 8];
    }
#pragma unroll
    for (int mt = 0; mt < 4; mt++)
#pragma unroll
      for (int nt = 0; nt < 4; nt++)
        acc[mt][nt] = __builtin_amdgcn_mfma_f32_16x16x32_bf16(af[mt], bfr[nt], acc[mt][nt], 0, 0, 0);
    if (have) {
#pragma unroll
      for (int j = 0; j < 4; j++) {
        bf16x4 o;
        o[0] = r0[j]; o[1] = r1[j]; o[2] = r2[j]; o[3] = r3[j];
        *(bf16x4*)&Bs[cur ^ 1][(dc0 + j) * 40 + kk4] = o;
      }
    }
    __syncthreads();
    cur ^= 1;
  }
#pragma unroll
  for (int mt = 0; mt < 4; mt++)
#pragma unroll
    for (int nt = 0; nt < 4; nt++) {
      int d = d0 + wn + nt * 16 + l15;
#pragma unroll
      for (int r = 0; r < 4; r++) {
        int e = e0 + wm + mt * 16 + q * 4 + r;
        g[((size_t)b * E_ + e) * D_ + d] = (__bf16)acc[mt][nt][r];
      }
    }
}

// ---------------- K3: preds = G_flat(64 x 196608) · W2^T, deep-K split MFMA ----------------
__global__ __launch_bounds__(256) void k3_mfma(const __bf16* __restrict__ g,
                                               const __bf16* __restrict__ w2,
                                               float* __restrict__ out) {
  __shared__ float sp[B_ * C_];
  const int tid = threadIdx.x;
  const int wave = tid >> 6, lane = tid & 63;
  const int q = lane >> 4, l15 = lane & 15;
  const int kbase = blockIdx.x * (K3K_ / K3NB_) + wave * 256;
  f32x4 acc[4] = {};

  for (int i = tid; i < B_ * C_; i += 256) sp[i] = 0.0f;

#pragma unroll
  for (int ks = 0; ks < 8; ks++) {
    int k = kbase + ks * 32 + q * 8;
    bf16x8 bfrag = *(const bf16x8*)&w2[(size_t)l15 * K3K_ + k];
#pragma unroll
    for (int mt = 0; mt < 4; mt++) {
      bf16x8 afrag = *(const bf16x8*)&g[(size_t)(mt * 16 + l15) * K3K_ + k];
      acc[mt] = __builtin_amdgcn_mfma_f32_16x16x32_bf16(afrag, bfrag, acc[mt], 0, 0, 0);
    }
  }
  __syncthreads();
  int c = l15;
  if (c < C_) {
#pragma unroll
    for (int mt = 0; mt < 4; mt++)
#pragma unroll
      for (int r = 0; r < 4; r++) {
        int b = mt * 16 + q * 4 + r;
        atomicAdd(&sp[b * C_ + c], acc[mt][r]);
      }
  }
  __syncthreads();
  const float scale = 1.0f / (196.0f * 256.0f);
  for (int i = tid; i < B_ * C_; i += 256) atomicAdd(&out[i], sp[i] * scale);
}

extern "C" void kernel_launch(void* const* d_in, const int* in_sizes, int n_in,
                              void* d_out, int out_size, void* d_ws, size_t ws_size,
                              hipStream_t stream) {
  const float* x    = (const float*)d_in[0];   // (64,196,768)
  const float* ag_w = (const float*)d_in[1];   // (256,768)
  const float* ag_b = (const float*)d_in[2];   // (256,)
  const float* lm_w = (const float*)d_in[3];   // (2560,768)
  float* out = (float*)d_out;                  // (64,10)

  char* ws = (char*)d_ws;
  const size_t XP_BYTES = (size_t)B_ * HWP_ * D_ * 2;
  const size_t W_BYTES  = (size_t)E_ * D_ * 2;
  const size_t ST_BYTES = (size_t)B_ * E_ * HWP_ * 2;
  const size_t G_BYTES  = (size_t)B_ * E_ * D_ * 2;
  __bf16* xhi = (__bf16*)(ws);
  __bf16* xlo = (__bf16*)(ws + XP_BYTES);
  __bf16* whi = (__bf16*)(ws + 2 * XP_BYTES);
  __bf16* wlo = (__bf16*)(ws + 2 * XP_BYTES + W_BYTES);
  __bf16* st  = (__bf16*)(ws + 2 * XP_BYTES + 2 * W_BYTES);
  __bf16* gb  = (__bf16*)(ws + 2 * XP_BYTES + 2 * W_BYTES + ST_BYTES);
  __bf16* w2  = (__bf16*)(ws + 2 * XP_BYTES + 2 * W_BYTES + ST_BYTES + G_BYTES);

  hipMemsetAsync(d_out, 0, (size_t)out_size * sizeof(float), stream);

  k0_x<<<dim3((B_ * HWP_ * D_) / 4 / 256), dim3(256), 0, stream>>>(x, xhi, xlo);
  k0_prep<<<dim3(192 + (16 * K3K_) / 4 / 256), dim3(256), 0, stream>>>(ag_w, whi, wlo, lm_w, w2);
  k1_signs<<<dim3(MP_ / 64, E_ / 64), dim3(256), 0, stream>>>(xhi, xlo, whi, wlo, ag_b, st);
  k2_g<<<dim3((E_ / 128) * (D_ / 128), B_), dim3(256), 0, stream>>>(st, xhi, gb);
  k3_mfma<<<dim3(K3NB_), dim3(256), 0, stream>>>(gb, w2, out);
}